// Round 5
// baseline (170.221 us; speedup 1.0000x reference)
//
#include <hip/hip_runtime.h>
#include <hip/hip_bf16.h>

#define NROW 50000
#define DIN 128
#define DM 256
#define HH 4
#define NC 40
#define BHN 200000
#define NBLK 782   // ceil(50000/64): 64 rows per 4-wave block

typedef float f32x4 __attribute__((ext_vector_type(4)));
typedef short bf16x8 __attribute__((ext_vector_type(8)));

__device__ __forceinline__ unsigned int pk2(float lo, float hi) {
    __hip_bfloat162 h = __float22bfloat162_rn(make_float2(lo, hi));
    return *(unsigned int*)&h;
}

// -------- prep: [0,196) scatter x4 | [196,212) Wpk | [212,224) Wgpk | [224,264) bias2+wsum --------
// Wpk  [kc][t][ln][8]: fragment-packed Win^T (A operand of swapped phase-1 MFMA).
// Wgpk [h][kc][t][ln][8]: fragment-packed gamma*Wh^T, pi-permuted k so the phase-3
//   A-fragment equals the lane-local packed Y words in natural order.
__global__ __launch_bounds__(256) void k_prep(const int* __restrict__ pi,
                                              const float* __restrict__ pv,
                                              const float* __restrict__ Win,
                                              const float* __restrict__ Wh,
                                              const float* __restrict__ gamma,
                                              const float* __restrict__ beta,
                                              const float* __restrict__ bh,
                                              float* __restrict__ vcol,
                                              unsigned short* __restrict__ Wpk,
                                              unsigned short* __restrict__ Wgpk,
                                              float* __restrict__ bias2,
                                              float* __restrict__ wsum) {
    const int bid = blockIdx.x, tid = threadIdx.x;
    if (bid < 196) {
        // vectorized scatter: 4 elements/thread; 50000%4==0 so the 4-group
        // never straddles a batch boundary -> one b for all 4.
        int k4 = (bid * 256 + tid) * 4;
        if (k4 < BHN) {
            int4   c4 = *(const int4*)&pi[2 * BHN + k4];
            float4 v4 = *(const float4*)&pv[k4];
            int b = (k4 >= 150000) ? 3 : (k4 >= 100000) ? 2 : (k4 >= 50000) ? 1 : 0;
            float* vb = vcol + b * NROW;
            vb[c4.x] = v4.x; vb[c4.y] = v4.y; vb[c4.z] = v4.z; vb[c4.w] = v4.w;
        }
    } else if (bid < 212) {
        int base = (bid - 196) * 512;
        #pragma unroll
        for (int qq = 0; qq < 2; ++qq) {
            int s = base + qq * 256 + tid;
            int ln = s & 63;
            int t  = (s >> 6) & 15;
            int kc = s >> 10;
            int n  = t * 16 + (ln & 15);
            int kb = kc * 32 + ((ln >> 4) << 3);
            union { unsigned int ui[4]; uint4 v4; } u;
            #pragma unroll
            for (int jj = 0; jj < 4; ++jj)
                u.ui[jj] = pk2(Win[(kb + 2 * jj) * DM + n], Win[(kb + 2 * jj + 1) * DM + n]);
            *(uint4*)&Wpk[s * 8] = u.v4;
        }
    } else if (bid < 224) {
        int base = (bid - 212) * 512;
        #pragma unroll
        for (int qq = 0; qq < 2; ++qq) {
            int s = base + qq * 256 + tid;
            int ln = s & 63;
            int u6 = s >> 6;
            int t  = u6 % 3;
            int v6 = u6 / 3;
            int kc = v6 & 7;
            int h  = v6 >> 3;
            int c  = t * 16 + (ln & 15);
            int dbase = h * 256 + kc * 32 + ((ln >> 4) << 2);   // h*256 + 32*kc + 4*q
            union { unsigned int ui[4]; uint4 v4; } u;
            if (c < NC) {
                #pragma unroll
                for (int jj = 0; jj < 4; ++jj) {
                    int dA = dbase + ((jj >> 1) << 4) + ((jj & 1) << 1);  // pi row for k-slot 2jj
                    u.ui[jj] = pk2(gamma[dA] * Wh[dA * NC + c],
                                   gamma[dA + 1] * Wh[(dA + 1) * NC + c]);
                }
            } else {
                u.v4 = make_uint4(0u, 0u, 0u, 0u);
            }
            *(uint4*)&Wgpk[s * 8] = u.v4;
        }
    } else {   // bias2[c] = bh[c] + sum_d beta[d]*Wh[d][c] ; wsum[c] = sum_d gamma[d]*Wh[d][c]
        __shared__ float redb[256], redw[256];
        int c = bid - 224;
        float sb = 0.f, sw = 0.f;
        #pragma unroll
        for (int q = 0; q < 4; ++q) {
            int d = tid + 256 * q;
            float w = Wh[d * NC + c];
            sb = fmaf(beta[d], w, sb);
            sw = fmaf(gamma[d], w, sw);
        }
        redb[tid] = sb; redw[tid] = sw;
        __syncthreads();
        for (int st = 128; st > 0; st >>= 1) {
            if (tid < st) { redb[tid] += redb[tid + st]; redw[tid] += redw[tid + st]; }
            __syncthreads();
        }
        if (tid == 0) { bias2[c] = bh[c] + redb[0]; wsum[c] = redw[0]; }
    }
}

// y-pass for head H over this half's 8 accG fragments: computes y once (f32),
// accumulates LN stats, packs to bf16 words ya[] (A-fragment order via pi-perm).
// bias read from LDS (bshm): broadcast ds_read, keeps b_in out of live registers.
#define Y_PASS(H, HALF) { \
    const float vh = vm[H]; \
    _Pragma("unroll") \
    for (int tt = 0; tt < 8; ++tt) { \
        float4 b4 = *(const float4*)&bshm[((HALF) * 8 + tt) * 16 + quad * 4]; \
        float y0 = vh * fmaxf(fmaf(vh, accG[tt][0], b4.x), 0.f); \
        float y1 = vh * fmaxf(fmaf(vh, accG[tt][1], b4.y), 0.f); \
        float y2 = vh * fmaxf(fmaf(vh, accG[tt][2], b4.z), 0.f); \
        float y3 = vh * fmaxf(fmaf(vh, accG[tt][3], b4.w), 0.f); \
        s_ += (y0 + y1) + (y2 + y3); \
        ss_ = fmaf(y0, y0, ss_); ss_ = fmaf(y1, y1, ss_); \
        ss_ = fmaf(y2, y2, ss_); ss_ = fmaf(y3, y3, ss_); \
        ya[tt * 2]     = pk2(y0, y1); \
        ya[tt * 2 + 1] = pk2(y2, y3); \
    } }

// -------- fused, BARRIER-FREE (R4 post-mortem: per-CU busy work ~50k cy but
// duration 134k cy — the gap is ~20 __syncthreads x vmcnt(0) drains of just-
// issued prefetches, with only 3 correlated block-streams/CU. Here: W fragments
// are loaded straight from L2 into MFMA operand registers (coalesced 16B/lane);
// no stage LDS, no cross-wave sharing, ONE barrier (bshm publish). 12 independent
// wave-streams/CU; compiler handles load->MFMA with counted vmcnt, never drains.
// Cost: weight traffic x4 (700MB via L1, ~18us floor) — still 3x under R4. --------
__global__ __launch_bounds__(256, 3) void k_fused(
    const float* __restrict__ feats, const float* __restrict__ appd,
    const unsigned short* __restrict__ Wpk,
    const unsigned short* __restrict__ Wgpk,
    const float* __restrict__ vcol,
    const float* __restrict__ b_in,
    const float* __restrict__ bias2,
    const float* __restrict__ wsum,
    float* __restrict__ out)
{
    __shared__ __align__(16) float bshm[256];               // b_in, LDS-resident

    const int tid = threadIdx.x;
    const int wv = tid >> 6;
    const int ln = tid & 63;
    const int quad = ln >> 4;
    const int lr = ln & 15;
    const int jw = blockIdx.x * 64 + wv * 16;
    const int ar = min(jw + lr, NROW - 1);

    bshm[tid] = b_in[tid];
    __syncthreads();                              // the ONLY barrier

    float vm[HH];
    #pragma unroll
    for (int h = 0; h < HH; ++h) vm[h] = vcol[h * NROW + ar];

    // per-lane fragment base pointers (lane ln reads bytes [ln*16, ln*16+16) of each frag)
    const unsigned short* wpL = Wpk  + (size_t)ln * 8;
    const unsigned short* wgL = Wgpk + (size_t)ln * 8;

    const f32x4 zero4 = {0.f, 0.f, 0.f, 0.f};
    float s_ = 0.f, ss_ = 0.f;
    f32x4 accO[3];
    #pragma unroll
    for (int t = 0; t < 3; ++t) accO[t] = zero4;
    f32x4 accG[8];
    unsigned int ya[16];

    #pragma unroll
    for (int half = 0; half < 2; ++half) {
        // fence: forbid CSE of half-1's afr loads with half-0's (keeps afr
        // live range confined to this half's phase 1 — the R3 spill lesson)
        if (half == 1) asm volatile("" ::: "memory");

        // ---- per-half afr pack (live only during this half's phase 1)
        unsigned int afr[8][4];
        {
            const float* rf = feats + (size_t)ar * DIN;
            const float* ra = appd  + (size_t)ar * DIN;
            #pragma unroll
            for (int kc = 0; kc < 8; ++kc) {
                const float* src = (kc < 4) ? rf : ra;
                const int ko = (kc & 3) * 32 + quad * 8;
                float4 x0 = *(const float4*)(src + ko);
                float4 x1 = *(const float4*)(src + ko + 4);
                afr[kc][0] = pk2(x0.x, x0.y);
                afr[kc][1] = pk2(x0.z, x0.w);
                afr[kc][2] = pk2(x1.x, x1.y);
                afr[kc][3] = pk2(x1.z, x1.w);
            }
        }

        // ---- phase 1 (this half): G cols [half*128, +128).
        // W frags direct from L2: 8-frag groups (32 VGPR in flight); scheduler
        // hoists the next group's loads under the current group's MFMAs.
        #pragma unroll
        for (int kc = 0; kc < 8; ++kc) {
            union { unsigned int ui[4]; bf16x8 v; } a;
            a.ui[0] = afr[kc][0]; a.ui[1] = afr[kc][1];
            a.ui[2] = afr[kc][2]; a.ui[3] = afr[kc][3];
            bf16x8 wf[8];
            #pragma unroll
            for (int th = 0; th < 8; ++th)
                wf[th] = *(const bf16x8*)&wpL[(size_t)(kc * 16 + half * 8 + th) * 512];
            #pragma unroll
            for (int th = 0; th < 8; ++th)
                accG[th] = __builtin_amdgcn_mfma_f32_16x16x32_bf16(
                    wf[th], a.v, (kc == 0) ? zero4 : accG[th], 0, 0, 0);
        }

        // ---- phase 2+3 (this half), per head: issue the 12 Wg frag loads,
        // hide their latency under Y_PASS's ~130 VALU ops, then 12 MFMAs.
        #pragma unroll
        for (int h = 0; h < HH; ++h) {
            bf16x8 wg[12];
            #pragma unroll
            for (int kcr = 0; kcr < 4; ++kcr)
                #pragma unroll
                for (int t3 = 0; t3 < 3; ++t3)
                    wg[kcr * 3 + t3] = *(const bf16x8*)
                        &wgL[(size_t)(((h * 8 + half * 4 + kcr) * 3 + t3)) * 512];
            Y_PASS(h, half)
            #pragma unroll
            for (int kcr = 0; kcr < 4; ++kcr) {
                union { unsigned int ui[4]; bf16x8 v; } af;
                af.ui[0] = ya[4 * kcr];     af.ui[1] = ya[4 * kcr + 1];
                af.ui[2] = ya[4 * kcr + 2]; af.ui[3] = ya[4 * kcr + 3];
                #pragma unroll
                for (int t3 = 0; t3 < 3; ++t3)
                    accO[t3] = __builtin_amdgcn_mfma_f32_16x16x32_bf16(
                        af.v, wg[kcr * 3 + t3], accO[t3], 0, 0, 0);
            }
        }
    }

    // ---- epilogue: finish LN stats (row jw+lr partials live on the 4 quad-lanes of lr),
    // fold LN affine: out = rs*acc + nm*wsum + bias2
    s_  += __shfl_xor(s_, 16);  s_  += __shfl_xor(s_, 32);
    ss_ += __shfl_xor(ss_, 16); ss_ += __shfl_xor(ss_, 32);
    float mm  = s_ * (1.f / 1024.f);
    float var = ss_ * (1.f / 1024.f) - mm * mm;
    float rs  = rsqrtf(var + 1e-5f);
    float nm  = -mm * rs;

    float rs_r[4], nm_r[4];
    #pragma unroll
    for (int rg = 0; rg < 4; ++rg) {
        int rloc = quad * 4 + rg;                 // lane rloc (quad 0, lr=rloc) has row jw+rloc
        rs_r[rg] = __shfl(rs, rloc);
        nm_r[rg] = __shfl(nm, rloc);
    }
    #pragma unroll
    for (int t = 0; t < 3; ++t) {
        int c = t * 16 + lr;
        if (c < NC) {
            float w2 = wsum[c], b2 = bias2[c];
            #pragma unroll
            for (int rg = 0; rg < 4; ++rg) {
                int row = jw + quad * 4 + rg;
                if (row < NROW)
                    out[(size_t)row * NC + c] = fmaf(rs_r[rg], accO[t][rg], fmaf(nm_r[rg], w2, b2));
            }
        }
    }
}

extern "C" void kernel_launch(void* const* d_in, const int* in_sizes, int n_in,
                              void* d_out, int out_size, void* d_ws, size_t ws_size,
                              hipStream_t stream) {
    const int*   pi    = (const int*)d_in[0];
    const float* pv    = (const float*)d_in[1];
    const float* feats = (const float*)d_in[2];
    const float* appd  = (const float*)d_in[3];
    const float* Win   = (const float*)d_in[4];
    const float* b_in  = (const float*)d_in[5];
    const float* gamma = (const float*)d_in[6];
    const float* beta  = (const float*)d_in[7];
    const float* Wh    = (const float*)d_in[8];
    const float* bh    = (const float*)d_in[9];
    float* out = (float*)d_out;

    char* w = (char*)d_ws;
    float*          vcolW  = (float*)w;                        // 800000 B
    unsigned short* WpkW   = (unsigned short*)(w + 800000);    // 131072 B
    unsigned short* WgpkW  = (unsigned short*)(w + 931072);    // 98304 B
    float*          bias2W = (float*)(w + 1029376);            // 160 B
    float*          wsumW  = (float*)(w + 1029536);            // 160 B

    k_prep<<<264, 256, 0, stream>>>(pi, pv, Win, Wh, gamma, beta, bh,
                                    vcolW, WpkW, WgpkW, bias2W, wsumW);
    k_fused<<<NBLK, 256, 0, stream>>>(feats, appd, WpkW, WgpkW, vcolW, b_in,
                                      bias2W, wsumW, out);
}

// Round 6
// 150.629 us; speedup vs baseline: 1.1301x; 1.1301x over previous
//
#include <hip/hip_runtime.h>
#include <hip/hip_bf16.h>

#define NROW 50000
#define DIN 128
#define DM 256
#define HH 4
#define NC 40
#define BHN 200000
#define NBLK 782   // ceil(50000/64): 64 rows per 4-wave block

typedef float f32x4 __attribute__((ext_vector_type(4)));
typedef short bf16x8 __attribute__((ext_vector_type(8)));

__device__ __forceinline__ unsigned int pk2(float lo, float hi) {
    __hip_bfloat162 h = __float22bfloat162_rn(make_float2(lo, hi));
    return *(unsigned int*)&h;
}

// -------- prep: [0,196) scatter x4 | [196,212) Wpk | [212,224) Wgpk | [224,264) bias2+wsum --------
// Wpk  [kc][t][ln][8]: fragment-packed Win^T (A operand of swapped phase-1 MFMA).
// Wgpk [h][kc][t][ln][8]: fragment-packed gamma*Wh^T, pi-permuted k so the phase-3
//   A-fragment equals the lane-local packed Y words in natural order.
__global__ __launch_bounds__(256) void k_prep(const int* __restrict__ pi,
                                              const float* __restrict__ pv,
                                              const float* __restrict__ Win,
                                              const float* __restrict__ Wh,
                                              const float* __restrict__ gamma,
                                              const float* __restrict__ beta,
                                              const float* __restrict__ bh,
                                              float* __restrict__ vcol,
                                              unsigned short* __restrict__ Wpk,
                                              unsigned short* __restrict__ Wgpk,
                                              float* __restrict__ bias2,
                                              float* __restrict__ wsum) {
    const int bid = blockIdx.x, tid = threadIdx.x;
    if (bid < 196) {
        // vectorized scatter: 4 elements/thread; 50000%4==0 so the 4-group
        // never straddles a batch boundary -> one b for all 4.
        int k4 = (bid * 256 + tid) * 4;
        if (k4 < BHN) {
            int4   c4 = *(const int4*)&pi[2 * BHN + k4];
            float4 v4 = *(const float4*)&pv[k4];
            int b = (k4 >= 150000) ? 3 : (k4 >= 100000) ? 2 : (k4 >= 50000) ? 1 : 0;
            float* vb = vcol + b * NROW;
            vb[c4.x] = v4.x; vb[c4.y] = v4.y; vb[c4.z] = v4.z; vb[c4.w] = v4.w;
        }
    } else if (bid < 212) {
        int base = (bid - 196) * 512;
        #pragma unroll
        for (int qq = 0; qq < 2; ++qq) {
            int s = base + qq * 256 + tid;
            int ln = s & 63;
            int t  = (s >> 6) & 15;
            int kc = s >> 10;
            int n  = t * 16 + (ln & 15);
            int kb = kc * 32 + ((ln >> 4) << 3);
            union { unsigned int ui[4]; uint4 v4; } u;
            #pragma unroll
            for (int jj = 0; jj < 4; ++jj)
                u.ui[jj] = pk2(Win[(kb + 2 * jj) * DM + n], Win[(kb + 2 * jj + 1) * DM + n]);
            *(uint4*)&Wpk[s * 8] = u.v4;
        }
    } else if (bid < 224) {
        int base = (bid - 212) * 512;
        #pragma unroll
        for (int qq = 0; qq < 2; ++qq) {
            int s = base + qq * 256 + tid;
            int ln = s & 63;
            int u6 = s >> 6;
            int t  = u6 % 3;
            int v6 = u6 / 3;
            int kc = v6 & 7;
            int h  = v6 >> 3;
            int c  = t * 16 + (ln & 15);
            int dbase = h * 256 + kc * 32 + ((ln >> 4) << 2);   // h*256 + 32*kc + 4*q
            union { unsigned int ui[4]; uint4 v4; } u;
            if (c < NC) {
                #pragma unroll
                for (int jj = 0; jj < 4; ++jj) {
                    int dA = dbase + ((jj >> 1) << 4) + ((jj & 1) << 1);  // pi row for k-slot 2jj
                    u.ui[jj] = pk2(gamma[dA] * Wh[dA * NC + c],
                                   gamma[dA + 1] * Wh[(dA + 1) * NC + c]);
                }
            } else {
                u.v4 = make_uint4(0u, 0u, 0u, 0u);
            }
            *(uint4*)&Wgpk[s * 8] = u.v4;
        }
    } else {   // bias2[c] = bh[c] + sum_d beta[d]*Wh[d][c] ; wsum[c] = sum_d gamma[d]*Wh[d][c]
        __shared__ float redb[256], redw[256];
        int c = bid - 224;
        float sb = 0.f, sw = 0.f;
        #pragma unroll
        for (int q = 0; q < 4; ++q) {
            int d = tid + 256 * q;
            float w = Wh[d * NC + c];
            sb = fmaf(beta[d], w, sb);
            sw = fmaf(gamma[d], w, sw);
        }
        redb[tid] = sb; redw[tid] = sw;
        __syncthreads();
        for (int st = 128; st > 0; st >>= 1) {
            if (tid < st) { redb[tid] += redb[tid + st]; redw[tid] += redw[tid + st]; }
            __syncthreads();
        }
        if (tid == 0) { bias2[c] = bh[c] + redb[0]; wsum[c] = redw[0]; }
    }
}

// y-pass for head H over this half's 8 accG fragments: computes y once (f32),
// accumulates LN stats, packs to bf16 words ya[] (A-fragment order via pi-perm).
// bias read from LDS (bshm): broadcast ds_read, keeps b_in out of live registers.
#define Y_PASS(H, HALF) { \
    const float vh = vm[H]; \
    _Pragma("unroll") \
    for (int tt = 0; tt < 8; ++tt) { \
        float4 b4 = *(const float4*)&bshm[((HALF) * 8 + tt) * 16 + quad * 4]; \
        float y0 = vh * fmaxf(fmaf(vh, accG[tt][0], b4.x), 0.f); \
        float y1 = vh * fmaxf(fmaf(vh, accG[tt][1], b4.y), 0.f); \
        float y2 = vh * fmaxf(fmaf(vh, accG[tt][2], b4.z), 0.f); \
        float y3 = vh * fmaxf(fmaf(vh, accG[tt][3], b4.w), 0.f); \
        s_ += (y0 + y1) + (y2 + y3); \
        ss_ = fmaf(y0, y0, ss_); ss_ = fmaf(y1, y1, ss_); \
        ss_ = fmaf(y2, y2, ss_); ss_ = fmaf(y3, y3, ss_); \
        ya[tt * 2]     = pk2(y0, y1); \
        ya[tt * 2 + 1] = pk2(y2, y3); \
    } }

// -------- fused, barrier-free (R4 lesson) + REGION-FENCED loads (R5 lesson:
// without fences the scheduler merged wf[8]+wg[12]+afr regions -> peak regs
// > 170 cap -> 37MB scratch spill). asm "memory" fences partition the memory
// ops: per-kc in phase 1 (<=32 wf regs in flight), per-head in phase 2/3
// (wg loaded in two 6-frag groups straddling Y_PASS, <=24 in flight).
// Peak live ~125 regs < 170. ONE barrier total (bshm publish). --------
__global__ __launch_bounds__(256, 3) void k_fused(
    const float* __restrict__ feats, const float* __restrict__ appd,
    const unsigned short* __restrict__ Wpk,
    const unsigned short* __restrict__ Wgpk,
    const float* __restrict__ vcol,
    const float* __restrict__ b_in,
    const float* __restrict__ bias2,
    const float* __restrict__ wsum,
    float* __restrict__ out)
{
    __shared__ __align__(16) float bshm[256];               // b_in, LDS-resident

    const int tid = threadIdx.x;
    const int wv = tid >> 6;
    const int ln = tid & 63;
    const int quad = ln >> 4;
    const int lr = ln & 15;
    const int jw = blockIdx.x * 64 + wv * 16;
    const int ar = min(jw + lr, NROW - 1);

    bshm[tid] = b_in[tid];
    __syncthreads();                              // the ONLY barrier

    float vm[HH];
    #pragma unroll
    for (int h = 0; h < HH; ++h) vm[h] = vcol[h * NROW + ar];

    // per-lane fragment base pointers (lane ln reads bytes [ln*16, ln*16+16) of each frag)
    const unsigned short* wpL = Wpk  + (size_t)ln * 8;
    const unsigned short* wgL = Wgpk + (size_t)ln * 8;

    const f32x4 zero4 = {0.f, 0.f, 0.f, 0.f};
    float s_ = 0.f, ss_ = 0.f;
    f32x4 accO[3];
    #pragma unroll
    for (int t = 0; t < 3; ++t) accO[t] = zero4;
    f32x4 accG[8];
    unsigned int ya[16];

    #pragma unroll
    for (int half = 0; half < 2; ++half) {
        // fence: forbid CSE of half-1's afr loads with half-0's (keeps afr
        // dead outside this half's phase 1 — the R3 spill lesson)
        if (half == 1) asm volatile("" ::: "memory");

        // ---- per-half afr pack (live only during this half's phase 1)
        unsigned int afr[8][4];
        {
            const float* rf = feats + (size_t)ar * DIN;
            const float* ra = appd  + (size_t)ar * DIN;
            #pragma unroll
            for (int kc = 0; kc < 8; ++kc) {
                const float* src = (kc < 4) ? rf : ra;
                const int ko = (kc & 3) * 32 + quad * 8;
                float4 x0 = *(const float4*)(src + ko);
                float4 x1 = *(const float4*)(src + ko + 4);
                afr[kc][0] = pk2(x0.x, x0.y);
                afr[kc][1] = pk2(x0.z, x0.w);
                afr[kc][2] = pk2(x1.x, x1.y);
                afr[kc][3] = pk2(x1.z, x1.w);
            }
        }

        // ---- phase 1 (this half): G cols [half*128, +128). W frags direct
        // from L2 into registers; per-kc fence caps in-flight wf at 32 regs.
        #pragma unroll
        for (int kc = 0; kc < 8; ++kc) {
            asm volatile("" ::: "memory");        // confine wf loads to this kc
            bf16x8 wf[8];
            #pragma unroll
            for (int th = 0; th < 8; ++th)
                wf[th] = *(const bf16x8*)&wpL[(size_t)(kc * 16 + half * 8 + th) * 512];
            union { unsigned int ui[4]; bf16x8 v; } a;
            a.ui[0] = afr[kc][0]; a.ui[1] = afr[kc][1];
            a.ui[2] = afr[kc][2]; a.ui[3] = afr[kc][3];
            #pragma unroll
            for (int th = 0; th < 8; ++th)
                accG[th] = __builtin_amdgcn_mfma_f32_16x16x32_bf16(
                    wf[th], a.v, (kc == 0) ? zero4 : accG[th], 0, 0, 0);
        }

        // ---- phase 2+3 (this half), per head: wg loads in two 6-frag groups
        // straddling Y_PASS (latency hidden under ~130 VALU ops); per-head
        // fence stops the next head's loads from merging in.
        #pragma unroll
        for (int h = 0; h < HH; ++h) {
            asm volatile("" ::: "memory");        // confine wg loads to this head
            bf16x8 wg[12];
            #pragma unroll
            for (int kcr = 0; kcr < 2; ++kcr)
                #pragma unroll
                for (int t3 = 0; t3 < 3; ++t3)
                    wg[kcr * 3 + t3] = *(const bf16x8*)
                        &wgL[(size_t)(((h * 8 + half * 4 + kcr) * 3 + t3)) * 512];
            Y_PASS(h, half)
            #pragma unroll
            for (int kcr = 2; kcr < 4; ++kcr)
                #pragma unroll
                for (int t3 = 0; t3 < 3; ++t3)
                    wg[kcr * 3 + t3] = *(const bf16x8*)
                        &wgL[(size_t)(((h * 8 + half * 4 + kcr) * 3 + t3)) * 512];
            #pragma unroll
            for (int kcr = 0; kcr < 4; ++kcr) {
                union { unsigned int ui[4]; bf16x8 v; } af;
                af.ui[0] = ya[4 * kcr];     af.ui[1] = ya[4 * kcr + 1];
                af.ui[2] = ya[4 * kcr + 2]; af.ui[3] = ya[4 * kcr + 3];
                #pragma unroll
                for (int t3 = 0; t3 < 3; ++t3)
                    accO[t3] = __builtin_amdgcn_mfma_f32_16x16x32_bf16(
                        af.v, wg[kcr * 3 + t3], accO[t3], 0, 0, 0);
            }
        }
    }

    // ---- epilogue: finish LN stats (row jw+lr partials live on the 4 quad-lanes of lr),
    // fold LN affine: out = rs*acc + nm*wsum + bias2
    s_  += __shfl_xor(s_, 16);  s_  += __shfl_xor(s_, 32);
    ss_ += __shfl_xor(ss_, 16); ss_ += __shfl_xor(ss_, 32);
    float mm  = s_ * (1.f / 1024.f);
    float var = ss_ * (1.f / 1024.f) - mm * mm;
    float rs  = rsqrtf(var + 1e-5f);
    float nm  = -mm * rs;

    float rs_r[4], nm_r[4];
    #pragma unroll
    for (int rg = 0; rg < 4; ++rg) {
        int rloc = quad * 4 + rg;                 // lane rloc (quad 0, lr=rloc) has row jw+rloc
        rs_r[rg] = __shfl(rs, rloc);
        nm_r[rg] = __shfl(nm, rloc);
    }
    #pragma unroll
    for (int t = 0; t < 3; ++t) {
        int c = t * 16 + lr;
        if (c < NC) {
            float w2 = wsum[c], b2 = bias2[c];
            #pragma unroll
            for (int rg = 0; rg < 4; ++rg) {
                int row = jw + quad * 4 + rg;
                if (row < NROW)
                    out[(size_t)row * NC + c] = fmaf(rs_r[rg], accO[t][rg], fmaf(nm_r[rg], w2, b2));
            }
        }
    }
}

extern "C" void kernel_launch(void* const* d_in, const int* in_sizes, int n_in,
                              void* d_out, int out_size, void* d_ws, size_t ws_size,
                              hipStream_t stream) {
    const int*   pi    = (const int*)d_in[0];
    const float* pv    = (const float*)d_in[1];
    const float* feats = (const float*)d_in[2];
    const float* appd  = (const float*)d_in[3];
    const float* Win   = (const float*)d_in[4];
    const float* b_in  = (const float*)d_in[5];
    const float* gamma = (const float*)d_in[6];
    const float* beta  = (const float*)d_in[7];
    const float* Wh    = (const float*)d_in[8];
    const float* bh    = (const float*)d_in[9];
    float* out = (float*)d_out;

    char* w = (char*)d_ws;
    float*          vcolW  = (float*)w;                        // 800000 B
    unsigned short* WpkW   = (unsigned short*)(w + 800000);    // 131072 B
    unsigned short* WgpkW  = (unsigned short*)(w + 931072);    // 98304 B
    float*          bias2W = (float*)(w + 1029376);            // 160 B
    float*          wsumW  = (float*)(w + 1029536);            // 160 B

    k_prep<<<264, 256, 0, stream>>>(pi, pv, Win, Wh, gamma, beta, bh,
                                    vcolW, WpkW, WgpkW, bias2W, wsumW);
    k_fused<<<NBLK, 256, 0, stream>>>(feats, appd, WpkW, WgpkW, vcolW, b_in,
                                      bias2W, wsumW, out);
}

// Round 7
// 149.206 us; speedup vs baseline: 1.1408x; 1.0095x over previous
//
#include <hip/hip_runtime.h>
#include <hip/hip_bf16.h>

#define NROW 50000
#define DIN 128
#define DM 256
#define HH 4
#define NC 40
#define BHN 200000
#define NBLK 3125  // 50000/16: 16 rows per 1-wave block (tail-free dispatch)

typedef float f32x4 __attribute__((ext_vector_type(4)));
typedef short bf16x8 __attribute__((ext_vector_type(8)));

__device__ __forceinline__ unsigned int pk2(float lo, float hi) {
    __hip_bfloat162 h = __float22bfloat162_rn(make_float2(lo, hi));
    return *(unsigned int*)&h;
}

// -------- prep: [0,196) scatter x4 | [196,212) Wpk | [212,224) Wgpk | [224,264) bias2+wsum --------
// Wpk  [kc][t][ln][8]: fragment-packed Win^T (A operand of swapped phase-1 MFMA).
// Wgpk [h][kc][t][ln][8]: fragment-packed gamma*Wh^T, pi-permuted k so the phase-3
//   A-fragment equals the lane-local packed Y words in natural order.
__global__ __launch_bounds__(256) void k_prep(const int* __restrict__ pi,
                                              const float* __restrict__ pv,
                                              const float* __restrict__ Win,
                                              const float* __restrict__ Wh,
                                              const float* __restrict__ gamma,
                                              const float* __restrict__ beta,
                                              const float* __restrict__ bh,
                                              float* __restrict__ vcol,
                                              unsigned short* __restrict__ Wpk,
                                              unsigned short* __restrict__ Wgpk,
                                              float* __restrict__ bias2,
                                              float* __restrict__ wsum) {
    const int bid = blockIdx.x, tid = threadIdx.x;
    if (bid < 196) {
        // vectorized scatter: 4 elements/thread; 50000%4==0 so the 4-group
        // never straddles a batch boundary -> one b for all 4.
        int k4 = (bid * 256 + tid) * 4;
        if (k4 < BHN) {
            int4   c4 = *(const int4*)&pi[2 * BHN + k4];
            float4 v4 = *(const float4*)&pv[k4];
            int b = (k4 >= 150000) ? 3 : (k4 >= 100000) ? 2 : (k4 >= 50000) ? 1 : 0;
            float* vb = vcol + b * NROW;
            vb[c4.x] = v4.x; vb[c4.y] = v4.y; vb[c4.z] = v4.z; vb[c4.w] = v4.w;
        }
    } else if (bid < 212) {
        int base = (bid - 196) * 512;
        #pragma unroll
        for (int qq = 0; qq < 2; ++qq) {
            int s = base + qq * 256 + tid;
            int ln = s & 63;
            int t  = (s >> 6) & 15;
            int kc = s >> 10;
            int n  = t * 16 + (ln & 15);
            int kb = kc * 32 + ((ln >> 4) << 3);
            union { unsigned int ui[4]; uint4 v4; } u;
            #pragma unroll
            for (int jj = 0; jj < 4; ++jj)
                u.ui[jj] = pk2(Win[(kb + 2 * jj) * DM + n], Win[(kb + 2 * jj + 1) * DM + n]);
            *(uint4*)&Wpk[s * 8] = u.v4;
        }
    } else if (bid < 224) {
        int base = (bid - 212) * 512;
        #pragma unroll
        for (int qq = 0; qq < 2; ++qq) {
            int s = base + qq * 256 + tid;
            int ln = s & 63;
            int u6 = s >> 6;
            int t  = u6 % 3;
            int v6 = u6 / 3;
            int kc = v6 & 7;
            int h  = v6 >> 3;
            int c  = t * 16 + (ln & 15);
            int dbase = h * 256 + kc * 32 + ((ln >> 4) << 2);   // h*256 + 32*kc + 4*q
            union { unsigned int ui[4]; uint4 v4; } u;
            if (c < NC) {
                #pragma unroll
                for (int jj = 0; jj < 4; ++jj) {
                    int dA = dbase + ((jj >> 1) << 4) + ((jj & 1) << 1);  // pi row for k-slot 2jj
                    u.ui[jj] = pk2(gamma[dA] * Wh[dA * NC + c],
                                   gamma[dA + 1] * Wh[(dA + 1) * NC + c]);
                }
            } else {
                u.v4 = make_uint4(0u, 0u, 0u, 0u);
            }
            *(uint4*)&Wgpk[s * 8] = u.v4;
        }
    } else {   // bias2[c] = bh[c] + sum_d beta[d]*Wh[d][c] ; wsum[c] = sum_d gamma[d]*Wh[d][c]
        __shared__ float redb[256], redw[256];
        int c = bid - 224;
        float sb = 0.f, sw = 0.f;
        #pragma unroll
        for (int q = 0; q < 4; ++q) {
            int d = tid + 256 * q;
            float w = Wh[d * NC + c];
            sb = fmaf(beta[d], w, sb);
            sw = fmaf(gamma[d], w, sw);
        }
        redb[tid] = sb; redw[tid] = sw;
        __syncthreads();
        for (int st = 128; st > 0; st >>= 1) {
            if (tid < st) { redb[tid] += redb[tid + st]; redw[tid] += redw[tid + st]; }
            __syncthreads();
        }
        if (tid == 0) { bias2[c] = bh[c] + redb[0]; wsum[c] = redw[0]; }
    }
}

// y-pass for head H over this half's 8 accG fragments: computes y once (f32),
// accumulates LN stats, packs to bf16 words ya[] (A-fragment order via pi-perm).
// bias read from LDS (bshm): broadcast ds_read, keeps b_in out of live registers.
#define Y_PASS(H, HALF) { \
    const float vh = vm[H]; \
    _Pragma("unroll") \
    for (int tt = 0; tt < 8; ++tt) { \
        float4 b4 = *(const float4*)&bshm[((HALF) * 8 + tt) * 16 + quad * 4]; \
        float y0 = vh * fmaxf(fmaf(vh, accG[tt][0], b4.x), 0.f); \
        float y1 = vh * fmaxf(fmaf(vh, accG[tt][1], b4.y), 0.f); \
        float y2 = vh * fmaxf(fmaf(vh, accG[tt][2], b4.z), 0.f); \
        float y3 = vh * fmaxf(fmaf(vh, accG[tt][3], b4.w), 0.f); \
        s_ += (y0 + y1) + (y2 + y3); \
        ss_ = fmaf(y0, y0, ss_); ss_ = fmaf(y1, y1, ss_); \
        ss_ = fmaf(y2, y2, ss_); ss_ = fmaf(y3, y3, ss_); \
        ya[tt * 2]     = pk2(y0, y1); \
        ya[tt * 2 + 1] = pk2(y2, y3); \
    } }

// -------- fused, 1-WAVE BLOCKS (R6 post-mortem: R0/R4/R6 — three disjoint sync
// structures — all plateau at 53-58us because 782x256t blocks at 3/CU residency
// = 768 resident of 782: the last 14 blocks run after a full drain -> duration
// ~= 2x single-batch time; Occupancy ~20% matches. R6 shares NOTHING across
// waves, so block size is pure scheduling granularity: 64-thread blocks, 3125
// blocks, 12 resident/CU at the same 170-reg cap -> 3072 of 3125 in batch 1,
// tail ~2%. Per-wave code, traffic, and reg pressure are byte-identical to R6.
// Barrier-free (one trivial intra-wave bshm sync); region-fenced loads (R5). --------
__global__ __launch_bounds__(64, 3) void k_fused(
    const float* __restrict__ feats, const float* __restrict__ appd,
    const unsigned short* __restrict__ Wpk,
    const unsigned short* __restrict__ Wgpk,
    const float* __restrict__ vcol,
    const float* __restrict__ b_in,
    const float* __restrict__ bias2,
    const float* __restrict__ wsum,
    float* __restrict__ out)
{
    __shared__ __align__(16) float bshm[256];               // b_in, LDS-resident

    const int tid = threadIdx.x;                            // = lane, 0..63
    const int ln = tid;
    const int quad = ln >> 4;
    const int lr = ln & 15;
    const int jw = blockIdx.x * 16;
    const int ar = min(jw + lr, NROW - 1);

    #pragma unroll
    for (int q = 0; q < 4; ++q) bshm[tid + 64 * q] = b_in[tid + 64 * q];
    __syncthreads();                              // intra-wave only (1 wave/block)

    float vm[HH];
    #pragma unroll
    for (int h = 0; h < HH; ++h) vm[h] = vcol[h * NROW + ar];

    // per-lane fragment base pointers (lane ln reads bytes [ln*16, ln*16+16) of each frag)
    const unsigned short* wpL = Wpk  + (size_t)ln * 8;
    const unsigned short* wgL = Wgpk + (size_t)ln * 8;

    const f32x4 zero4 = {0.f, 0.f, 0.f, 0.f};
    float s_ = 0.f, ss_ = 0.f;
    f32x4 accO[3];
    #pragma unroll
    for (int t = 0; t < 3; ++t) accO[t] = zero4;
    f32x4 accG[8];
    unsigned int ya[16];

    #pragma unroll
    for (int half = 0; half < 2; ++half) {
        // fence: forbid CSE of half-1's afr loads with half-0's (keeps afr
        // dead outside this half's phase 1 — the R3 spill lesson)
        if (half == 1) asm volatile("" ::: "memory");

        // ---- per-half afr pack (live only during this half's phase 1)
        unsigned int afr[8][4];
        {
            const float* rf = feats + (size_t)ar * DIN;
            const float* ra = appd  + (size_t)ar * DIN;
            #pragma unroll
            for (int kc = 0; kc < 8; ++kc) {
                const float* src = (kc < 4) ? rf : ra;
                const int ko = (kc & 3) * 32 + quad * 8;
                float4 x0 = *(const float4*)(src + ko);
                float4 x1 = *(const float4*)(src + ko + 4);
                afr[kc][0] = pk2(x0.x, x0.y);
                afr[kc][1] = pk2(x0.z, x0.w);
                afr[kc][2] = pk2(x1.x, x1.y);
                afr[kc][3] = pk2(x1.z, x1.w);
            }
        }

        // ---- phase 1 (this half): G cols [half*128, +128). W frags direct
        // from L2 into registers; per-kc fence caps in-flight wf at 32 regs.
        #pragma unroll
        for (int kc = 0; kc < 8; ++kc) {
            asm volatile("" ::: "memory");        // confine wf loads to this kc
            bf16x8 wf[8];
            #pragma unroll
            for (int th = 0; th < 8; ++th)
                wf[th] = *(const bf16x8*)&wpL[(size_t)(kc * 16 + half * 8 + th) * 512];
            union { unsigned int ui[4]; bf16x8 v; } a;
            a.ui[0] = afr[kc][0]; a.ui[1] = afr[kc][1];
            a.ui[2] = afr[kc][2]; a.ui[3] = afr[kc][3];
            #pragma unroll
            for (int th = 0; th < 8; ++th)
                accG[th] = __builtin_amdgcn_mfma_f32_16x16x32_bf16(
                    wf[th], a.v, (kc == 0) ? zero4 : accG[th], 0, 0, 0);
        }

        // ---- phase 2+3 (this half), per head: wg loads in two 6-frag groups
        // straddling Y_PASS (latency hidden under ~130 VALU ops); per-head
        // fence stops the next head's loads from merging in.
        #pragma unroll
        for (int h = 0; h < HH; ++h) {
            asm volatile("" ::: "memory");        // confine wg loads to this head
            bf16x8 wg[12];
            #pragma unroll
            for (int kcr = 0; kcr < 2; ++kcr)
                #pragma unroll
                for (int t3 = 0; t3 < 3; ++t3)
                    wg[kcr * 3 + t3] = *(const bf16x8*)
                        &wgL[(size_t)(((h * 8 + half * 4 + kcr) * 3 + t3)) * 512];
            Y_PASS(h, half)
            #pragma unroll
            for (int kcr = 2; kcr < 4; ++kcr)
                #pragma unroll
                for (int t3 = 0; t3 < 3; ++t3)
                    wg[kcr * 3 + t3] = *(const bf16x8*)
                        &wgL[(size_t)(((h * 8 + half * 4 + kcr) * 3 + t3)) * 512];
            #pragma unroll
            for (int kcr = 0; kcr < 4; ++kcr) {
                union { unsigned int ui[4]; bf16x8 v; } af;
                af.ui[0] = ya[4 * kcr];     af.ui[1] = ya[4 * kcr + 1];
                af.ui[2] = ya[4 * kcr + 2]; af.ui[3] = ya[4 * kcr + 3];
                #pragma unroll
                for (int t3 = 0; t3 < 3; ++t3)
                    accO[t3] = __builtin_amdgcn_mfma_f32_16x16x32_bf16(
                        af.v, wg[kcr * 3 + t3], accO[t3], 0, 0, 0);
            }
        }
    }

    // ---- epilogue: finish LN stats (row jw+lr partials live on the 4 quad-lanes of lr),
    // fold LN affine: out = rs*acc + nm*wsum + bias2
    s_  += __shfl_xor(s_, 16);  s_  += __shfl_xor(s_, 32);
    ss_ += __shfl_xor(ss_, 16); ss_ += __shfl_xor(ss_, 32);
    float mm  = s_ * (1.f / 1024.f);
    float var = ss_ * (1.f / 1024.f) - mm * mm;
    float rs  = rsqrtf(var + 1e-5f);
    float nm  = -mm * rs;

    float rs_r[4], nm_r[4];
    #pragma unroll
    for (int rg = 0; rg < 4; ++rg) {
        int rloc = quad * 4 + rg;                 // lane rloc (quad 0, lr=rloc) has row jw+rloc
        rs_r[rg] = __shfl(rs, rloc);
        nm_r[rg] = __shfl(nm, rloc);
    }
    #pragma unroll
    for (int t = 0; t < 3; ++t) {
        int c = t * 16 + lr;
        if (c < NC) {
            float w2 = wsum[c], b2 = bias2[c];
            #pragma unroll
            for (int rg = 0; rg < 4; ++rg) {
                int row = jw + quad * 4 + rg;
                if (row < NROW)
                    out[(size_t)row * NC + c] = fmaf(rs_r[rg], accO[t][rg], fmaf(nm_r[rg], w2, b2));
            }
        }
    }
}

extern "C" void kernel_launch(void* const* d_in, const int* in_sizes, int n_in,
                              void* d_out, int out_size, void* d_ws, size_t ws_size,
                              hipStream_t stream) {
    const int*   pi    = (const int*)d_in[0];
    const float* pv    = (const float*)d_in[1];
    const float* feats = (const float*)d_in[2];
    const float* appd  = (const float*)d_in[3];
    const float* Win   = (const float*)d_in[4];
    const float* b_in  = (const float*)d_in[5];
    const float* gamma = (const float*)d_in[6];
    const float* beta  = (const float*)d_in[7];
    const float* Wh    = (const float*)d_in[8];
    const float* bh    = (const float*)d_in[9];
    float* out = (float*)d_out;

    char* w = (char*)d_ws;
    float*          vcolW  = (float*)w;                        // 800000 B
    unsigned short* WpkW   = (unsigned short*)(w + 800000);    // 131072 B
    unsigned short* WgpkW  = (unsigned short*)(w + 931072);    // 98304 B
    float*          bias2W = (float*)(w + 1029376);            // 160 B
    float*          wsumW  = (float*)(w + 1029536);            // 160 B

    k_prep<<<264, 256, 0, stream>>>(pi, pv, Win, Wh, gamma, beta, bh,
                                    vcolW, WpkW, WgpkW, bias2W, wsumW);
    k_fused<<<NBLK, 64, 0, stream>>>(feats, appd, WpkW, WgpkW, vcolW, b_in,
                                     bias2W, wsumW, out);
}

// Round 8
// 141.157 us; speedup vs baseline: 1.2059x; 1.0570x over previous
//
#include <hip/hip_runtime.h>
#include <hip/hip_bf16.h>

#define NROW 50000
#define DIN 128
#define DM 256
#define HH 4
#define NC 40
#define BHN 200000
#define NBLK 1563  // ceil(50000/32): 32 rows per 1-wave block (2 row-tiles)

typedef float f32x4 __attribute__((ext_vector_type(4)));
typedef short bf16x8 __attribute__((ext_vector_type(8)));

__device__ __forceinline__ unsigned int pk2(float lo, float hi) {
    __hip_bfloat162 h = __float22bfloat162_rn(make_float2(lo, hi));
    return *(unsigned int*)&h;
}

// -------- prep: [0,196) scatter x4 | [196,212) Wpk | [212,224) Wgpk | [224,264) bias2+wsum --------
// Wpk  [kc][t][ln][8]: fragment-packed Win^T (A operand of swapped phase-1 MFMA).
// Wgpk [h][kc][t][ln][8]: fragment-packed gamma*Wh^T, pi-permuted k so the phase-3
//   A-fragment equals the lane-local packed Y words in natural order.
__global__ __launch_bounds__(256) void k_prep(const int* __restrict__ pi,
                                              const float* __restrict__ pv,
                                              const float* __restrict__ Win,
                                              const float* __restrict__ Wh,
                                              const float* __restrict__ gamma,
                                              const float* __restrict__ beta,
                                              const float* __restrict__ bh,
                                              float* __restrict__ vcol,
                                              unsigned short* __restrict__ Wpk,
                                              unsigned short* __restrict__ Wgpk,
                                              float* __restrict__ bias2,
                                              float* __restrict__ wsum) {
    const int bid = blockIdx.x, tid = threadIdx.x;
    if (bid < 196) {
        // vectorized scatter: 4 elements/thread; 50000%4==0 so the 4-group
        // never straddles a batch boundary -> one b for all 4.
        int k4 = (bid * 256 + tid) * 4;
        if (k4 < BHN) {
            int4   c4 = *(const int4*)&pi[2 * BHN + k4];
            float4 v4 = *(const float4*)&pv[k4];
            int b = (k4 >= 150000) ? 3 : (k4 >= 100000) ? 2 : (k4 >= 50000) ? 1 : 0;
            float* vb = vcol + b * NROW;
            vb[c4.x] = v4.x; vb[c4.y] = v4.y; vb[c4.z] = v4.z; vb[c4.w] = v4.w;
        }
    } else if (bid < 212) {
        int base = (bid - 196) * 512;
        #pragma unroll
        for (int qq = 0; qq < 2; ++qq) {
            int s = base + qq * 256 + tid;
            int ln = s & 63;
            int t  = (s >> 6) & 15;
            int kc = s >> 10;
            int n  = t * 16 + (ln & 15);
            int kb = kc * 32 + ((ln >> 4) << 3);
            union { unsigned int ui[4]; uint4 v4; } u;
            #pragma unroll
            for (int jj = 0; jj < 4; ++jj)
                u.ui[jj] = pk2(Win[(kb + 2 * jj) * DM + n], Win[(kb + 2 * jj + 1) * DM + n]);
            *(uint4*)&Wpk[s * 8] = u.v4;
        }
    } else if (bid < 224) {
        int base = (bid - 212) * 512;
        #pragma unroll
        for (int qq = 0; qq < 2; ++qq) {
            int s = base + qq * 256 + tid;
            int ln = s & 63;
            int u6 = s >> 6;
            int t  = u6 % 3;
            int v6 = u6 / 3;
            int kc = v6 & 7;
            int h  = v6 >> 3;
            int c  = t * 16 + (ln & 15);
            int dbase = h * 256 + kc * 32 + ((ln >> 4) << 2);   // h*256 + 32*kc + 4*q
            union { unsigned int ui[4]; uint4 v4; } u;
            if (c < NC) {
                #pragma unroll
                for (int jj = 0; jj < 4; ++jj) {
                    int dA = dbase + ((jj >> 1) << 4) + ((jj & 1) << 1);  // pi row for k-slot 2jj
                    u.ui[jj] = pk2(gamma[dA] * Wh[dA * NC + c],
                                   gamma[dA + 1] * Wh[(dA + 1) * NC + c]);
                }
            } else {
                u.v4 = make_uint4(0u, 0u, 0u, 0u);
            }
            *(uint4*)&Wgpk[s * 8] = u.v4;
        }
    } else {   // bias2[c] = bh[c] + sum_d beta[d]*Wh[d][c] ; wsum[c] = sum_d gamma[d]*Wh[d][c]
        __shared__ float redb[256], redw[256];
        int c = bid - 224;
        float sb = 0.f, sw = 0.f;
        #pragma unroll
        for (int q = 0; q < 4; ++q) {
            int d = tid + 256 * q;
            float w = Wh[d * NC + c];
            sb = fmaf(beta[d], w, sb);
            sw = fmaf(gamma[d], w, sw);
        }
        redb[tid] = sb; redw[tid] = sw;
        __syncthreads();
        for (int st = 128; st > 0; st >>= 1) {
            if (tid < st) { redb[tid] += redb[tid + st]; redw[tid] += redw[tid + st]; }
            __syncthreads();
        }
        if (tid == 0) { bias2[c] = bh[c] + redb[0]; wsum[c] = redw[0]; }
    }
}

// y-pass for one row-tile/head: y once (f32), LN stats inline, pack to bf16 ya[]
// (A-fragment order via pi-perm). bias from LDS (broadcast ds_read).
#define Y_PASS(VH, ACC, S, SS, HALF) { \
    _Pragma("unroll") \
    for (int tt = 0; tt < 8; ++tt) { \
        float4 b4 = *(const float4*)&bshm[((HALF) * 8 + tt) * 16 + quad * 4]; \
        float y0 = (VH) * fmaxf(fmaf((VH), ACC[tt][0], b4.x), 0.f); \
        float y1 = (VH) * fmaxf(fmaf((VH), ACC[tt][1], b4.y), 0.f); \
        float y2 = (VH) * fmaxf(fmaf((VH), ACC[tt][2], b4.z), 0.f); \
        float y3 = (VH) * fmaxf(fmaf((VH), ACC[tt][3], b4.w), 0.f); \
        S += (y0 + y1) + (y2 + y3); \
        SS = fmaf(y0, y0, SS); SS = fmaf(y1, y1, SS); \
        SS = fmaf(y2, y2, SS); SS = fmaf(y3, y3, SS); \
        ya[tt * 2]     = pk2(y0, y1); \
        ya[tt * 2 + 1] = pk2(y2, y3); \
    } }

// 12 MFMAs for one row-tile's head chunk from the SHARED wg fragments.
#define HEAD_MFMA(ACCO) { \
    _Pragma("unroll") \
    for (int kcr = 0; kcr < 4; ++kcr) { \
        union { unsigned int ui[4]; bf16x8 v; } af; \
        af.ui[0] = ya[4 * kcr];     af.ui[1] = ya[4 * kcr + 1]; \
        af.ui[2] = ya[4 * kcr + 2]; af.ui[3] = ya[4 * kcr + 3]; \
        _Pragma("unroll") \
        for (int t3 = 0; t3 < 3; ++t3) \
            ACCO[t3] = __builtin_amdgcn_mfma_f32_16x16x32_bf16( \
                af.v, wg[kcr * 3 + t3], ACCO[t3], 0, 0, 0); \
    } }

// per-row-tile afr pack (live only inside this half's phase 1)
#define AFR_PACK(AFR, AR) { \
    const float* rf = feats + (size_t)(AR) * DIN; \
    const float* ra = appd  + (size_t)(AR) * DIN; \
    _Pragma("unroll") \
    for (int kc = 0; kc < 8; ++kc) { \
        const float* src = (kc < 4) ? rf : ra; \
        const int ko = (kc & 3) * 32 + quad * 8; \
        float4 x0 = *(const float4*)(src + ko); \
        float4 x1 = *(const float4*)(src + ko + 4); \
        AFR[kc][0] = pk2(x0.x, x0.y); \
        AFR[kc][1] = pk2(x0.z, x0.w); \
        AFR[kc][2] = pk2(x1.x, x1.y); \
        AFR[kc][3] = pk2(x1.z, x1.w); \
    } }

// -------- fused, 2 ROW-TILES PER WAVE (R7 post-mortem: four disjoint schedules
// all plateau at 53-58us; duration/resident-waves ~45k cy/wave => per-wave
// load->MFMA chains bind, and every variant had the same 14KB-weights/16-rows
// ratio. Here each wave computes 32 rows sharing every weight fragment:
// 8 loads feed 16 MFMAs (ph1), 12 loads feed 24 MFMAs + 2 Y_PASSes (ph2/3).
// Weight traffic and stall-chain count per output HALVE (700->350MB).
// Needs 256-reg cap: __launch_bounds__(64,2) (2 waves/SIMD, 8 blocks/CU;
// grid 6.1/CU -> still single-batch). Fences exactly as R7 (no-spill proven). --------
__global__ __launch_bounds__(64, 2) void k_fused(
    const float* __restrict__ feats, const float* __restrict__ appd,
    const unsigned short* __restrict__ Wpk,
    const unsigned short* __restrict__ Wgpk,
    const float* __restrict__ vcol,
    const float* __restrict__ b_in,
    const float* __restrict__ bias2,
    const float* __restrict__ wsum,
    float* __restrict__ out)
{
    __shared__ __align__(16) float bshm[256];               // b_in, LDS-resident

    const int tid = threadIdx.x;                            // = lane, 0..63
    const int ln = tid;
    const int quad = ln >> 4;
    const int lr = ln & 15;
    const int jw = blockIdx.x * 32;
    const int ar0 = min(jw + lr, NROW - 1);
    const int ar1 = min(jw + 16 + lr, NROW - 1);

    #pragma unroll
    for (int q = 0; q < 4; ++q) bshm[tid + 64 * q] = b_in[tid + 64 * q];
    __syncthreads();                              // intra-wave only (1 wave/block)

    float vm0[HH], vm1[HH];
    #pragma unroll
    for (int h = 0; h < HH; ++h) {
        vm0[h] = vcol[h * NROW + ar0];
        vm1[h] = vcol[h * NROW + ar1];
    }

    // per-lane fragment base pointers (lane ln reads bytes [ln*16, ln*16+16) of each frag)
    const unsigned short* wpL = Wpk  + (size_t)ln * 8;
    const unsigned short* wgL = Wgpk + (size_t)ln * 8;

    const f32x4 zero4 = {0.f, 0.f, 0.f, 0.f};
    float s0 = 0.f, ss0 = 0.f, s1 = 0.f, ss1 = 0.f;
    f32x4 accO0[3], accO1[3];
    #pragma unroll
    for (int t = 0; t < 3; ++t) { accO0[t] = zero4; accO1[t] = zero4; }
    f32x4 accG0[8], accG1[8];
    unsigned int ya[16];

    #pragma unroll
    for (int half = 0; half < 2; ++half) {
        // fence: forbid CSE of half-1's afr loads with half-0's (R3 spill lesson)
        if (half == 1) asm volatile("" ::: "memory");

        unsigned int afr0[8][4], afr1[8][4];
        AFR_PACK(afr0, ar0)
        AFR_PACK(afr1, ar1)

        // ---- phase 1 (this half): G cols [half*128, +128). Each 8-load wf group
        // feeds SIXTEEN MFMAs (both row-tiles). Per-kc fence caps in-flight regs.
        #pragma unroll
        for (int kc = 0; kc < 8; ++kc) {
            asm volatile("" ::: "memory");        // confine wf loads to this kc
            bf16x8 wf[8];
            #pragma unroll
            for (int th = 0; th < 8; ++th)
                wf[th] = *(const bf16x8*)&wpL[(size_t)(kc * 16 + half * 8 + th) * 512];
            union { unsigned int ui[4]; bf16x8 v; } a0, a1;
            a0.ui[0] = afr0[kc][0]; a0.ui[1] = afr0[kc][1];
            a0.ui[2] = afr0[kc][2]; a0.ui[3] = afr0[kc][3];
            a1.ui[0] = afr1[kc][0]; a1.ui[1] = afr1[kc][1];
            a1.ui[2] = afr1[kc][2]; a1.ui[3] = afr1[kc][3];
            #pragma unroll
            for (int th = 0; th < 8; ++th) {
                accG0[th] = __builtin_amdgcn_mfma_f32_16x16x32_bf16(
                    wf[th], a0.v, (kc == 0) ? zero4 : accG0[th], 0, 0, 0);
                accG1[th] = __builtin_amdgcn_mfma_f32_16x16x32_bf16(
                    wf[th], a1.v, (kc == 0) ? zero4 : accG1[th], 0, 0, 0);
            }
        }

        // ---- phase 2+3 (this half), per head: ONE wg load set (12 frags) serves
        // both row-tiles (24 MFMAs + 2 Y_PASSes). rt1's Y_PASS VALU overlaps
        // rt0's MFMAs on the matrix pipe. Per-head fence confines the loads.
        #pragma unroll
        for (int h = 0; h < HH; ++h) {
            asm volatile("" ::: "memory");        // confine wg loads to this head
            bf16x8 wg[12];
            #pragma unroll
            for (int kcr = 0; kcr < 2; ++kcr)
                #pragma unroll
                for (int t3 = 0; t3 < 3; ++t3)
                    wg[kcr * 3 + t3] = *(const bf16x8*)
                        &wgL[(size_t)(((h * 8 + half * 4 + kcr) * 3 + t3)) * 512];
            Y_PASS(vm0[h], accG0, s0, ss0, half)  // hides wg latency
            #pragma unroll
            for (int kcr = 2; kcr < 4; ++kcr)
                #pragma unroll
                for (int t3 = 0; t3 < 3; ++t3)
                    wg[kcr * 3 + t3] = *(const bf16x8*)
                        &wgL[(size_t)(((h * 8 + half * 4 + kcr) * 3 + t3)) * 512];
            HEAD_MFMA(accO0)
            Y_PASS(vm1[h], accG1, s1, ss1, half)  // overlaps rt0's MFMAs
            HEAD_MFMA(accO1)
        }
    }

    // ---- epilogue per row-tile: finish LN stats, fold affine:
    // out = rs*acc + nm*wsum + bias2
    s0  += __shfl_xor(s0, 16);  s0  += __shfl_xor(s0, 32);
    ss0 += __shfl_xor(ss0, 16); ss0 += __shfl_xor(ss0, 32);
    s1  += __shfl_xor(s1, 16);  s1  += __shfl_xor(s1, 32);
    ss1 += __shfl_xor(ss1, 16); ss1 += __shfl_xor(ss1, 32);
    float mm0  = s0 * (1.f / 1024.f);
    float rs0  = rsqrtf(ss0 * (1.f / 1024.f) - mm0 * mm0 + 1e-5f);
    float nm0  = -mm0 * rs0;
    float mm1  = s1 * (1.f / 1024.f);
    float rs1  = rsqrtf(ss1 * (1.f / 1024.f) - mm1 * mm1 + 1e-5f);
    float nm1  = -mm1 * rs1;

    float rs_r0[4], nm_r0[4], rs_r1[4], nm_r1[4];
    #pragma unroll
    for (int rg = 0; rg < 4; ++rg) {
        int rloc = quad * 4 + rg;                 // lane rloc (quad 0, lr=rloc) has row jw+rloc
        rs_r0[rg] = __shfl(rs0, rloc);
        nm_r0[rg] = __shfl(nm0, rloc);
        rs_r1[rg] = __shfl(rs1, rloc);
        nm_r1[rg] = __shfl(nm1, rloc);
    }
    #pragma unroll
    for (int t = 0; t < 3; ++t) {
        int c = t * 16 + lr;
        if (c < NC) {
            float w2 = wsum[c], b2 = bias2[c];
            #pragma unroll
            for (int rg = 0; rg < 4; ++rg) {
                int row0 = jw + quad * 4 + rg;
                int row1 = row0 + 16;
                if (row0 < NROW)
                    out[(size_t)row0 * NC + c] = fmaf(rs_r0[rg], accO0[t][rg], fmaf(nm_r0[rg], w2, b2));
                if (row1 < NROW)
                    out[(size_t)row1 * NC + c] = fmaf(rs_r1[rg], accO1[t][rg], fmaf(nm_r1[rg], w2, b2));
            }
        }
    }
}

extern "C" void kernel_launch(void* const* d_in, const int* in_sizes, int n_in,
                              void* d_out, int out_size, void* d_ws, size_t ws_size,
                              hipStream_t stream) {
    const int*   pi    = (const int*)d_in[0];
    const float* pv    = (const float*)d_in[1];
    const float* feats = (const float*)d_in[2];
    const float* appd  = (const float*)d_in[3];
    const float* Win   = (const float*)d_in[4];
    const float* b_in  = (const float*)d_in[5];
    const float* gamma = (const float*)d_in[6];
    const float* beta  = (const float*)d_in[7];
    const float* Wh    = (const float*)d_in[8];
    const float* bh    = (const float*)d_in[9];
    float* out = (float*)d_out;

    char* w = (char*)d_ws;
    float*          vcolW  = (float*)w;                        // 800000 B
    unsigned short* WpkW   = (unsigned short*)(w + 800000);    // 131072 B
    unsigned short* WgpkW  = (unsigned short*)(w + 931072);    // 98304 B
    float*          bias2W = (float*)(w + 1029376);            // 160 B
    float*          wsumW  = (float*)(w + 1029536);            // 160 B

    k_prep<<<264, 256, 0, stream>>>(pi, pv, Win, Wh, gamma, beta, bh,
                                    vcolW, WpkW, WgpkW, bias2W, wsumW);
    k_fused<<<NBLK, 64, 0, stream>>>(feats, appd, WpkW, WgpkW, vcolW, b_in,
                                     bias2W, wsumW, out);
}